// Round 8
// baseline (74.160 us; speedup 1.0000x reference)
//
#include <hip/hip_runtime.h>
#include <math.h>

#define BATCH 2
#define NNODE 512
#define DIN   128
#define DOUT  128
#define DE    32
#define NEG   0.2f
#define TI    16      // i-rows per score block
#define TJ    64      // j-cols per score block (4 waves x 16)
#define TIB   8       // i-rows per agg block

typedef __attribute__((ext_vector_type(8))) short bf16x8;
typedef __attribute__((ext_vector_type(4))) float f32x4;

__device__ inline short f2bf(float f) {   // RNE f32 -> bf16
    union { float f; unsigned u; } v; v.f = f;
    unsigned r = v.u + 0x7fffu + ((v.u >> 16) & 1u);
    return (short)(r >> 16);
}

// ---------------------------------------------------------------------------
// Kernel 1: x_l = x@W_l + b_l ; x_r = x@W_r + b_r   (4 rows/block)
// ---------------------------------------------------------------------------
__global__ __launch_bounds__(256) void xlr_kernel(
    const float* __restrict__ x,  const float* __restrict__ Wl,
    const float* __restrict__ bl, const float* __restrict__ Wr,
    const float* __restrict__ br, float* __restrict__ xl,
    float* __restrict__ xr)
{
    const int r0 = blockIdx.x * 4;
    const int d  = threadIdx.x & 127;
    const int hv = threadIdx.x >> 7;
    __shared__ float xs[4][DIN];
    for (int idx = threadIdx.x; idx < 4 * DIN; idx += 256)
        xs[idx >> 7][idx & 127] = x[(size_t)r0 * DIN + idx];
    __syncthreads();
    const int ra = 2 * hv, rb = ra + 1;
    float al0 = bl[d], al1 = al0, ar0 = br[d], ar1 = ar0;
    #pragma unroll 4
    for (int k = 0; k < DIN; ++k) {
        const float wl = Wl[k * DOUT + d], wr = Wr[k * DOUT + d];
        const float xa = xs[ra][k], xb = xs[rb][k];
        al0 = fmaf(xa, wl, al0); al1 = fmaf(xb, wl, al1);
        ar0 = fmaf(xa, wr, ar0); ar1 = fmaf(xb, wr, ar1);
    }
    xl[(size_t)(r0 + ra) * DOUT + d] = al0;
    xl[(size_t)(r0 + rb) * DOUT + d] = al1;
    xr[(size_t)(r0 + ra) * DOUT + d] = ar0;
    xr[(size_t)(r0 + rb) * DOUT + d] = ar1;
}

// ---------------------------------------------------------------------------
// Kernel 2 (score): block = (b, 16-i tile, 64-j tile) -> masked scores to ws.
// x_l j-tile staged in LDS ONCE, reused by all 16 i's (kills the 512 MB of
// redundant per-i x_l traffic round 4 had). MFMA mapping identical to the
// verified round-4 kernel.
// ---------------------------------------------------------------------------
__global__ __launch_bounds__(256, 2) void score_kernel(
    const float* __restrict__ xl, const float* __restrict__ xr,
    const void* __restrict__ adjv, const float* __restrict__ e,
    const float* __restrict__ We, const float* __restrict__ att,
    float* __restrict__ sc)
{
    const int bid = blockIdx.x;          // 512 blocks: (b, iT:32, jT:8)
    const int jT  = bid & 7;
    const int iT  = (bid >> 3) & 31;
    const int b   = bid >> 8;
    const int i0  = iT * TI, j0 = jT * TJ;
    const int t    = threadIdx.x;
    const int wave = t >> 6;
    const int lane = t & 63;
    const int col  = lane & 15;
    const int g    = lane >> 4;

    __shared__ short WeT_s[DOUT][DE];        // 8 KB  [d][k] bf16
    __shared__ float xl_s[TJ][DOUT + 4];     // 33 KB (pad: 2-way conflicts only)
    __shared__ float xr_s[TI][DOUT];         // 8 KB
    __shared__ float att_s[DOUT];
    __shared__ int   mflag[2];

    if (t < 2) mflag[t] = 0;
    for (int idx = t; idx < DE * DOUT; idx += 256) {
        const int k = idx >> 7, d = idx & 127;
        WeT_s[d][k] = f2bf(We[idx]);
    }
    for (int idx = t; idx < TJ * DOUT; idx += 256) {
        const int jj = idx >> 7, d = idx & 127;
        xl_s[jj][d] = xl[(size_t)(b * NNODE + j0 + jj) * DOUT + d];
    }
    for (int idx = t; idx < TI * DOUT; idx += 256) {
        const int ii = idx >> 7, d = idx & 127;
        xr_s[ii][d] = xr[(size_t)(b * NNODE + i0 + ii) * DOUT + d];
    }
    if (t < DOUT) att_s[t] = att[t];
    // adj dtype probe (first 16 KB, L2-resident)
    {
        const unsigned* aw = (const unsigned*)adjv;
        unsigned sawF = 0, sawG = 0;
        #pragma unroll
        for (int k = 0; k < 16; ++k) {
            const unsigned w = aw[t + 256 * k];
            sawF |= (w == 0x3f800000u);
            sawG |= (w > 1u);
        }
        if (sawF) atomicOr(&mflag[0], 1);
        if (sawG) atomicOr(&mflag[1], 1);
    }
    __syncthreads();
    const int byteMode = (!mflag[0] && mflag[1]) ? 1 : 0;

    bf16x8 bf[8];
    float  atv[8];
    #pragma unroll
    for (int dt = 0; dt < 8; ++dt) {
        bf[dt]  = *(const bf16x8*)&WeT_s[dt * 16 + col][g * 8];
        atv[dt] = att_s[dt * 16 + col];
    }

    const int jw = j0 + wave * 16;           // this wave's 16-j tile
    for (int i = 0; i < TI; ++i) {
        const int ig = i0 + i;
        const float* ap = e + ((size_t)(b * NNODE + ig) * NNODE + jw + col) * DE + g * 8;
        const f32x4 a0 = *(const f32x4*)ap;
        const f32x4 a1 = *(const f32x4*)(ap + 4);
        bf16x8 af;
        af[0] = f2bf(a0[0]); af[1] = f2bf(a0[1]);
        af[2] = f2bf(a0[2]); af[3] = f2bf(a0[3]);
        af[4] = f2bf(a1[0]); af[5] = f2bf(a1[1]);
        af[6] = f2bf(a1[2]); af[7] = f2bf(a1[3]);

        f32x4 z = {0.f, 0.f, 0.f, 0.f};
        f32x4 c[8];
        #pragma unroll
        for (int dt = 0; dt < 8; ++dt)
            c[dt] = __builtin_amdgcn_mfma_f32_16x16x32_bf16(af, bf[dt], z, 0, 0, 0);

        float part[4] = {0.f, 0.f, 0.f, 0.f};
        #pragma unroll
        for (int dt = 0; dt < 8; ++dt) {
            const int d = dt * 16 + col;
            const float xrv = xr_s[i][d];
            #pragma unroll
            for (int r = 0; r < 4; ++r) {
                const int jloc = wave * 16 + g * 4 + r;
                float p = c[dt][r] + xrv + xl_s[jloc][d];
                p = p > 0.f ? p : NEG * p;
                part[r] = fmaf(atv[dt], p, part[r]);
            }
        }
        #pragma unroll
        for (int r = 0; r < 4; ++r) {
            part[r] += __shfl_xor(part[r], 1, 64);
            part[r] += __shfl_xor(part[r], 2, 64);
            part[r] += __shfl_xor(part[r], 4, 64);
            part[r] += __shfl_xor(part[r], 8, 64);
        }
        if (col == 0) {
            const int jb = jw + g * 4;
            const unsigned char* aB = (const unsigned char*)adjv + (size_t)(b * NNODE + ig) * NNODE;
            const unsigned*      aW = (const unsigned*)adjv + (size_t)(b * NNODE + ig) * NNODE;
            float4 v;
            {
                float* vp = (float*)&v;
                #pragma unroll
                for (int r = 0; r < 4; ++r) {
                    const int j = jb + r;
                    const bool conn = (j == ig) ||
                        (byteMode ? (aB[j] != 0) : (aW[j] != 0));
                    vp[r] = conn ? part[r] : -1e30f;
                }
            }
            *(float4*)&sc[(size_t)(b * NNODE + ig) * NNODE + jb] = v;
        }
    }
}

// ---------------------------------------------------------------------------
// Kernel 3 (agg): block = (b, 8-i tile, d-half 64). Stage 8 score rows in
// LDS, wave-local softmax (rows wave, wave+4), then alpha @ x_l with x_l
// reads shared across rows + 2-way j unroll (independent FMA chains).
// ---------------------------------------------------------------------------
__global__ __launch_bounds__(256) void agg_kernel(
    const float* __restrict__ xl, const float* __restrict__ sc,
    const void* __restrict__ adjv, const void* __restrict__ maskv,
    const float* __restrict__ bias, float* __restrict__ out)
{
    const int bid = blockIdx.x;          // 256 blocks: (b, iT:64, dh:2)
    const int dh  = bid & 1;
    const int iT  = (bid >> 1) & 63;
    const int b   = bid >> 7;
    const int i0  = iT * TIB, d0 = dh * 64;
    const int t    = threadIdx.x;
    const int wave = t >> 6;
    const int lane = t & 63;

    __shared__ float al_s[TIB][NNODE];   // 16 KB
    __shared__ int   mflag[2];

    if (t < 2) mflag[t] = 0;
    {
        const unsigned* aw = (const unsigned*)adjv;
        unsigned sawF = 0, sawG = 0;
        #pragma unroll
        for (int k = 0; k < 16; ++k) {
            const unsigned w = aw[t + 256 * k];
            sawF |= (w == 0x3f800000u);
            sawG |= (w > 1u);
        }
        if (sawF) atomicOr(&mflag[0], 1);
        if (sawG) atomicOr(&mflag[1], 1);
    }
    for (int idx = t; idx < TIB * NNODE; idx += 256) {
        const int r = idx >> 9, jj = idx & 511;
        al_s[r][jj] = sc[(size_t)(b * NNODE + i0 + r) * NNODE + jj];
    }
    __syncthreads();
    const int byteMode = (!mflag[0] && mflag[1]) ? 1 : 0;

    // wave-local softmax on rows wave and wave+4 (no further barriers needed:
    // each wave consumes only the alpha rows it wrote)
    float invs[2];
    #pragma unroll
    for (int q = 0; q < 2; ++q) {
        const int rr = wave + 4 * q;
        float v[8], m = -1e30f;
        #pragma unroll
        for (int k = 0; k < 8; ++k) {
            v[k] = al_s[rr][lane + 64 * k];
            m = fmaxf(m, v[k]);
        }
        #pragma unroll
        for (int off = 32; off; off >>= 1) m = fmaxf(m, __shfl_xor(m, off, 64));
        float s = 0.f;
        #pragma unroll
        for (int k = 0; k < 8; ++k) {
            const float ex = __expf(v[k] - m);
            al_s[rr][lane + 64 * k] = ex;
            s += ex;
        }
        #pragma unroll
        for (int off = 32; off; off >>= 1) s += __shfl_xor(s, off, 64);
        invs[q] = 1.f / s;
    }

    // aggregation: rows (wave, wave+4), cols d0+lane
    const int d = d0 + lane;
    const float* xb = xl + (size_t)b * NNODE * DOUT + d;
    float a0 = 0.f, a0b = 0.f, a1 = 0.f, a1b = 0.f;
    for (int j = 0; j < NNODE; j += 2) {
        const float x0 = xb[(size_t)j * DOUT];
        const float x1 = xb[(size_t)(j + 1) * DOUT];
        a0  = fmaf(al_s[wave][j],     x0, a0);
        a0b = fmaf(al_s[wave][j + 1], x1, a0b);
        a1  = fmaf(al_s[wave + 4][j],     x0, a1);
        a1b = fmaf(al_s[wave + 4][j + 1], x1, a1b);
    }
    const float bv = bias[d];
    #pragma unroll
    for (int q = 0; q < 2; ++q) {
        const int row = i0 + wave + 4 * q;
        const int mi  = b * NNODE + row;
        const bool mv = byteMode ? (((const unsigned char*)maskv)[mi] != 0)
                                 : (((const unsigned*)maskv)[mi] != 0);
        float val = (q == 0 ? a0 + a0b : a1 + a1b) * invs[q] + bv;
        if (!mv) val = 0.f;
        val = val / (1.f + __expf(-val));    // silu
        out[(size_t)mi * DOUT + d] = val;
    }
}

// ---------------------------------------------------------------------------
extern "C" void kernel_launch(void* const* d_in, const int* in_sizes, int n_in,
                              void* d_out, int out_size, void* d_ws, size_t ws_size,
                              hipStream_t stream)
{
    const float* x    = (const float*)d_in[0];
    const void*  adj  = d_in[1];
    const float* e    = (const float*)d_in[2];
    const void*  mask = d_in[3];
    const float* Wl   = (const float*)d_in[4];
    const float* bl   = (const float*)d_in[5];
    const float* Wr   = (const float*)d_in[6];
    const float* br   = (const float*)d_in[7];
    const float* We   = (const float*)d_in[8];
    const float* att  = (const float*)d_in[9];
    const float* bias = (const float*)d_in[10];
    float*       out  = (float*)d_out;

    float* xl = (float*)d_ws;                              // 512 KB
    float* xr = xl + (size_t)BATCH * NNODE * DOUT;         // 512 KB
    float* sc = xr + (size_t)BATCH * NNODE * DOUT;         // 2 MB scores

    xlr_kernel<<<(BATCH * NNODE) / 4, 256, 0, stream>>>(x, Wl, bl, Wr, br, xl, xr);
    score_kernel<<<BATCH * (NNODE / TI) * (NNODE / TJ), 256, 0, stream>>>(
        xl, xr, adj, e, We, att, sc);
    agg_kernel<<<BATCH * (NNODE / TIB) * 2, 256, 0, stream>>>(
        xl, sc, adj, mask, bias, out);
}

// Round 9
// 58.579 us; speedup vs baseline: 1.2660x; 1.2660x over previous
//
#include <hip/hip_runtime.h>
#include <math.h>

#define BATCH 2
#define NNODE 512
#define DIN   128
#define DOUT  128
#define DE    32
#define NEG   0.2f
#define TI    8       // i-rows per score block
#define TJ    64      // j-cols per score block (4 waves x 16)
#define TIB   8       // i-rows per agg block

typedef __attribute__((ext_vector_type(8))) short bf16x8;
typedef __attribute__((ext_vector_type(4))) float f32x4;

__device__ inline short f2bf(float f) {   // RNE f32 -> bf16
    union { float f; unsigned u; } v; v.f = f;
    unsigned r = v.u + 0x7fffu + ((v.u >> 16) & 1u);
    return (short)(r >> 16);
}

// ---------------------------------------------------------------------------
// Kernel 1: x_l = x@W_l + b_l ; x_r = x@W_r + b_r   (4 rows/block)
// ---------------------------------------------------------------------------
__global__ __launch_bounds__(256) void xlr_kernel(
    const float* __restrict__ x,  const float* __restrict__ Wl,
    const float* __restrict__ bl, const float* __restrict__ Wr,
    const float* __restrict__ br, float* __restrict__ xl,
    float* __restrict__ xr)
{
    const int r0 = blockIdx.x * 4;
    const int d  = threadIdx.x & 127;
    const int hv = threadIdx.x >> 7;
    __shared__ float xs[4][DIN];
    for (int idx = threadIdx.x; idx < 4 * DIN; idx += 256)
        xs[idx >> 7][idx & 127] = x[(size_t)r0 * DIN + idx];
    __syncthreads();
    const int ra = 2 * hv, rb = ra + 1;
    float al0 = bl[d], al1 = al0, ar0 = br[d], ar1 = ar0;
    #pragma unroll 4
    for (int k = 0; k < DIN; ++k) {
        const float wl = Wl[k * DOUT + d], wr = Wr[k * DOUT + d];
        const float xa = xs[ra][k], xb = xs[rb][k];
        al0 = fmaf(xa, wl, al0); al1 = fmaf(xb, wl, al1);
        ar0 = fmaf(xa, wr, ar0); ar1 = fmaf(xb, wr, ar1);
    }
    xl[(size_t)(r0 + ra) * DOUT + d] = al0;
    xl[(size_t)(r0 + rb) * DOUT + d] = al1;
    xr[(size_t)(r0 + ra) * DOUT + d] = ar0;
    xr[(size_t)(r0 + rb) * DOUT + d] = ar1;
}

// ---------------------------------------------------------------------------
// Kernel 2 (score): block = (b, 8-i tile, 64-j tile). xl held in 32 REGISTERS
// per lane (the (jloc,d) set each lane needs is i-invariant) -> no xl LDS, no
// bank conflicts, ~13 KB LDS, 1024 blocks, 4 waves/EU. Depth-1 e-prefetch.
// MFMA fragment mapping identical to the verified round-4/8 kernel.
// ---------------------------------------------------------------------------
__global__ __launch_bounds__(256, 4) void score_kernel(
    const float* __restrict__ xl, const float* __restrict__ xr,
    const void* __restrict__ adjv, const float* __restrict__ e,
    const float* __restrict__ We, const float* __restrict__ att,
    float* __restrict__ sc)
{
    const int bid = blockIdx.x;          // 1024 blocks: (b, iT:64, jT:8)
    const int jT  = bid & 7;
    const int iT  = (bid >> 3) & 63;
    const int b   = bid >> 9;
    const int i0  = iT * TI, j0 = jT * TJ;
    const int t    = threadIdx.x;
    const int wave = t >> 6;
    const int lane = t & 63;
    const int col  = lane & 15;
    const int g    = lane >> 4;

    __shared__ short WeT_s[DOUT][DE];        // 8 KB  [d][k] bf16
    __shared__ float xr_s[TI][DOUT];         // 4 KB
    __shared__ float att_s[DOUT];
    __shared__ int   mflag[2];

    if (t < 2) mflag[t] = 0;
    for (int idx = t; idx < DE * DOUT; idx += 256) {
        const int k = idx >> 7, d = idx & 127;
        WeT_s[d][k] = f2bf(We[idx]);
    }
    for (int idx = t; idx < TI * DOUT; idx += 256) {
        const int ii = idx >> 7, d = idx & 127;
        xr_s[ii][d] = xr[(size_t)(b * NNODE + i0 + ii) * DOUT + d];
    }
    if (t < DOUT) att_s[t] = att[t];
    // adj dtype probe (first 16 KB, L2-resident)
    {
        const unsigned* aw = (const unsigned*)adjv;
        unsigned sawF = 0, sawG = 0;
        #pragma unroll
        for (int k = 0; k < 16; ++k) {
            const unsigned w = aw[t + 256 * k];
            sawF |= (w == 0x3f800000u);
            sawG |= (w > 1u);
        }
        if (sawF) atomicOr(&mflag[0], 1);
        if (sawG) atomicOr(&mflag[1], 1);
    }

    // xl -> registers: lane needs xl[j0 + wave*16 + g*4 + r][dt*16 + col],
    // invariant across the i-loop. 32 f32 regs. (L2-resident, one-time.)
    float xlv[32];
    {
        const float* xb = xl + (size_t)(b * NNODE + j0 + wave * 16 + g * 4) * DOUT + col;
        #pragma unroll
        for (int dt = 0; dt < 8; ++dt)
            #pragma unroll
            for (int r = 0; r < 4; ++r)
                xlv[dt * 4 + r] = xb[(size_t)r * DOUT + dt * 16];
    }
    __syncthreads();
    const int byteMode = (!mflag[0] && mflag[1]) ? 1 : 0;

    bf16x8 bf[8];
    float  atv[8];
    #pragma unroll
    for (int dt = 0; dt < 8; ++dt) {
        bf[dt]  = *(const bf16x8*)&WeT_s[dt * 16 + col][g * 8];
        atv[dt] = att_s[dt * 16 + col];
    }

    const int jw = j0 + wave * 16;           // this wave's 16-j tile
    const float* ebase = e + ((size_t)(b * NNODE + i0) * NNODE + jw + col) * DE + g * 8;
    const size_t estep = (size_t)NNODE * DE; // per-i stride

    f32x4 a0 = *(const f32x4*)ebase;
    f32x4 a1 = *(const f32x4*)(ebase + 4);

    for (int i = 0; i < TI; ++i) {
        f32x4 a0n, a1n;
        if (i + 1 < TI) {                    // depth-1 prefetch of next i
            const float* apn = ebase + (size_t)(i + 1) * estep;
            a0n = *(const f32x4*)apn;
            a1n = *(const f32x4*)(apn + 4);
        }
        bf16x8 af;
        af[0] = f2bf(a0[0]); af[1] = f2bf(a0[1]);
        af[2] = f2bf(a0[2]); af[3] = f2bf(a0[3]);
        af[4] = f2bf(a1[0]); af[5] = f2bf(a1[1]);
        af[6] = f2bf(a1[2]); af[7] = f2bf(a1[3]);

        const f32x4 z = {0.f, 0.f, 0.f, 0.f};
        float part[4] = {0.f, 0.f, 0.f, 0.f};
        #pragma unroll
        for (int dt = 0; dt < 8; ++dt) {     // per-dt MFMA -> epilogue (low liveness)
            const f32x4 c = __builtin_amdgcn_mfma_f32_16x16x32_bf16(af, bf[dt], z, 0, 0, 0);
            const float xrv = xr_s[i][dt * 16 + col];
            #pragma unroll
            for (int r = 0; r < 4; ++r) {
                float p = c[r] + xrv + xlv[dt * 4 + r];
                p = fmaxf(p, NEG * p);       // leaky_relu, 2 ops
                part[r] = fmaf(atv[dt], p, part[r]);
            }
        }
        #pragma unroll
        for (int r = 0; r < 4; ++r) {
            part[r] += __shfl_xor(part[r], 1, 64);
            part[r] += __shfl_xor(part[r], 2, 64);
            part[r] += __shfl_xor(part[r], 4, 64);
            part[r] += __shfl_xor(part[r], 8, 64);
        }
        if (col == 0) {
            const int ig = i0 + i;
            const int jb = jw + g * 4;
            const unsigned char* aB = (const unsigned char*)adjv + (size_t)(b * NNODE + ig) * NNODE;
            const unsigned*      aW = (const unsigned*)adjv + (size_t)(b * NNODE + ig) * NNODE;
            float4 v;
            float* vp = (float*)&v;
            #pragma unroll
            for (int r = 0; r < 4; ++r) {
                const int j = jb + r;
                const bool conn = (j == ig) ||
                    (byteMode ? (aB[j] != 0) : (aW[j] != 0));
                vp[r] = conn ? part[r] : -1e30f;
            }
            *(float4*)&sc[(size_t)(b * NNODE + ig) * NNODE + jb] = v;
        }
        a0 = a0n; a1 = a1n;
    }
}

// ---------------------------------------------------------------------------
// Kernel 3 (agg): block = (b, 8-i tile, d-half 64). Stage 8 score rows in
// LDS, wave-local softmax (rows wave, wave+4), then alpha @ x_l with x_l
// reads shared across rows + 2-way j unroll (independent FMA chains).
// ---------------------------------------------------------------------------
__global__ __launch_bounds__(256) void agg_kernel(
    const float* __restrict__ xl, const float* __restrict__ sc,
    const void* __restrict__ adjv, const void* __restrict__ maskv,
    const float* __restrict__ bias, float* __restrict__ out)
{
    const int bid = blockIdx.x;          // 256 blocks: (b, iT:64, dh:2)
    const int dh  = bid & 1;
    const int iT  = (bid >> 1) & 63;
    const int b   = bid >> 7;
    const int i0  = iT * TIB, d0 = dh * 64;
    const int t    = threadIdx.x;
    const int wave = t >> 6;
    const int lane = t & 63;

    __shared__ float al_s[TIB][NNODE];   // 16 KB
    __shared__ int   mflag[2];

    if (t < 2) mflag[t] = 0;
    {
        const unsigned* aw = (const unsigned*)adjv;
        unsigned sawF = 0, sawG = 0;
        #pragma unroll
        for (int k = 0; k < 16; ++k) {
            const unsigned w = aw[t + 256 * k];
            sawF |= (w == 0x3f800000u);
            sawG |= (w > 1u);
        }
        if (sawF) atomicOr(&mflag[0], 1);
        if (sawG) atomicOr(&mflag[1], 1);
    }
    for (int idx = t; idx < TIB * NNODE; idx += 256) {
        const int r = idx >> 9, jj = idx & 511;
        al_s[r][jj] = sc[(size_t)(b * NNODE + i0 + r) * NNODE + jj];
    }
    __syncthreads();
    const int byteMode = (!mflag[0] && mflag[1]) ? 1 : 0;

    // wave-local softmax on rows wave and wave+4 (no further barriers needed:
    // each wave consumes only the alpha rows it wrote)
    float invs[2];
    #pragma unroll
    for (int q = 0; q < 2; ++q) {
        const int rr = wave + 4 * q;
        float v[8], m = -1e30f;
        #pragma unroll
        for (int k = 0; k < 8; ++k) {
            v[k] = al_s[rr][lane + 64 * k];
            m = fmaxf(m, v[k]);
        }
        #pragma unroll
        for (int off = 32; off; off >>= 1) m = fmaxf(m, __shfl_xor(m, off, 64));
        float s = 0.f;
        #pragma unroll
        for (int k = 0; k < 8; ++k) {
            const float ex = __expf(v[k] - m);
            al_s[rr][lane + 64 * k] = ex;
            s += ex;
        }
        #pragma unroll
        for (int off = 32; off; off >>= 1) s += __shfl_xor(s, off, 64);
        invs[q] = 1.f / s;
    }

    // aggregation: rows (wave, wave+4), cols d0+lane
    const int d = d0 + lane;
    const float* xb = xl + (size_t)b * NNODE * DOUT + d;
    float a0 = 0.f, a0b = 0.f, a1 = 0.f, a1b = 0.f;
    for (int j = 0; j < NNODE; j += 2) {
        const float x0 = xb[(size_t)j * DOUT];
        const float x1 = xb[(size_t)(j + 1) * DOUT];
        a0  = fmaf(al_s[wave][j],     x0, a0);
        a0b = fmaf(al_s[wave][j + 1], x1, a0b);
        a1  = fmaf(al_s[wave + 4][j],     x0, a1);
        a1b = fmaf(al_s[wave + 4][j + 1], x1, a1b);
    }
    const float bv = bias[d];
    #pragma unroll
    for (int q = 0; q < 2; ++q) {
        const int row = i0 + wave + 4 * q;
        const int mi  = b * NNODE + row;
        const bool mv = byteMode ? (((const unsigned char*)maskv)[mi] != 0)
                                 : (((const unsigned*)maskv)[mi] != 0);
        float val = (q == 0 ? a0 + a0b : a1 + a1b) * invs[q] + bv;
        if (!mv) val = 0.f;
        val = val / (1.f + __expf(-val));    // silu
        out[(size_t)mi * DOUT + d] = val;
    }
}

// ---------------------------------------------------------------------------
extern "C" void kernel_launch(void* const* d_in, const int* in_sizes, int n_in,
                              void* d_out, int out_size, void* d_ws, size_t ws_size,
                              hipStream_t stream)
{
    const float* x    = (const float*)d_in[0];
    const void*  adj  = d_in[1];
    const float* e    = (const float*)d_in[2];
    const void*  mask = d_in[3];
    const float* Wl   = (const float*)d_in[4];
    const float* bl   = (const float*)d_in[5];
    const float* Wr   = (const float*)d_in[6];
    const float* br   = (const float*)d_in[7];
    const float* We   = (const float*)d_in[8];
    const float* att  = (const float*)d_in[9];
    const float* bias = (const float*)d_in[10];
    float*       out  = (float*)d_out;

    float* xl = (float*)d_ws;                              // 512 KB
    float* xr = xl + (size_t)BATCH * NNODE * DOUT;         // 512 KB
    float* sc = xr + (size_t)BATCH * NNODE * DOUT;         // 2 MB scores

    xlr_kernel<<<(BATCH * NNODE) / 4, 256, 0, stream>>>(x, Wl, bl, Wr, br, xl, xr);
    score_kernel<<<BATCH * (NNODE / TI) * (NNODE / TJ), 256, 0, stream>>>(
        xl, xr, adj, e, We, att, sc);
    agg_kernel<<<BATCH * (NNODE / TIB) * 2, 256, 0, stream>>>(
        xl, sc, adj, mask, bias, out);
}